// Round 9
// baseline (243.477 us; speedup 1.0000x reference)
//
#include <hip/hip_runtime.h>

// CompositeValueNoise R9: counting sort with 8-byte packed points
// {qx,qy,qz @14b bucket-relative, orig @21b}; 1024 buckets (16x8x8);
// scatter uses shfl wave-scan (3 barriers) and writes 64B-aligned runs;
// main kernel fine-sorts into 4 sub-cells, stages per-fine-cell grid
// slices (889 float4 = 14 KB) to LDS, evaluates LDS-only, streams results
// coalesced; permute epilogue out[i] = tmp[rank[i]].

#define NB 1024                // 16 x 8 x 8 buckets
#define PTS_PER_BLK 8192
#define CHUNK 32
#define SC_THREADS 1024
#define SC_PPT (PTS_PER_BLK / SC_THREADS)   // 8
#define H_THREADS 256
#define H_PPT (PTS_PER_BLK / H_THREADS)     // 32
#define TILE 2432              // mean seg 1953, sd ~44 -> +10.8 sigma
#define MT 1024

__device__ __forceinline__ int bucket_of(float px, float py, float pz) {
    int ix = min(max((int)(px * 16.0f), 0), 15);
    int iy = min(max((int)(py * 8.0f), 0), 7);
    int iz = min(max((int)(pz * 8.0f), 0), 7);
    return (ix * 8 + iy) * 8 + iz;
}

__global__ void __launch_bounds__(H_THREADS)
cvn_hist(const float* __restrict__ x, int* __restrict__ P, int n) {
    __shared__ int cnt[NB];
    int t = threadIdx.x;
    for (int q = t; q < NB; q += H_THREADS) cnt[q] = 0;
    __syncthreads();
    int base = blockIdx.x * PTS_PER_BLK;
    for (int k = 0; k < H_PPT; ++k) {
        int i = base + k * H_THREADS + t;
        if (i < n)
            atomicAdd(&cnt[bucket_of(x[3 * i], x[3 * i + 1], x[3 * i + 2])], 1);
    }
    __syncthreads();
    int* Pb = P + (size_t)blockIdx.x * NB;
    for (int q = t; q < NB; q += H_THREADS) Pb[q] = cnt[q];
}

__global__ void __launch_bounds__(256)
cvn_scan_a(const int* __restrict__ P, int* __restrict__ S, int nblk) {
    int q = blockIdx.x * 256 + threadIdx.x;
    int c = blockIdx.y;
    int b0 = c * CHUNK, b1 = min(b0 + CHUNK, nblk);
    int s = 0;
    for (int b = b0; b < b1; ++b) s += P[(size_t)b * NB + q];
    S[(size_t)c * NB + q] = s;
}

// After: S[c][q] = Texcl[q] + exclusive chunk prefix; S[0][q] = bucket base.
__global__ void __launch_bounds__(NB)
cvn_scan_b(int* __restrict__ S, int nch) {
    __shared__ int part[NB];
    int t = threadIdx.x;
    int acc = 0;
    for (int c = 0; c < nch; ++c) {
        int v = S[(size_t)c * NB + t];
        S[(size_t)c * NB + t] = acc;
        acc += v;
    }
    part[t] = acc;
    __syncthreads();
    for (int off = 1; off < NB; off <<= 1) {
        int v = (t >= off) ? part[t - off] : 0;
        __syncthreads();
        if (t >= off) part[t] += v;
        __syncthreads();
    }
    int texcl = (t == 0) ? 0 : part[t - 1];
    for (int c = 0; c < nch; ++c) S[(size_t)c * NB + t] += texcl;
}

__global__ void __launch_bounds__(256)
cvn_scan_c(int* __restrict__ P, const int* __restrict__ S, int nblk) {
    int q = blockIdx.x * 256 + threadIdx.x;
    int c = blockIdx.y;
    int b0 = c * CHUNK, b1 = min(b0 + CHUNK, nblk);
    int run = S[(size_t)c * NB + q];
    for (int b = b0; b < b1; ++b) {
        int v = P[(size_t)b * NB + q];
        P[(size_t)b * NB + q] = run;
        run += v;
    }
}

// Pack a point: qx,qy,qz are 14-bit bucket-relative coords; orig 21 bits.
// lo = qx | qy<<14 | (qz&0xF)<<28 ; hi = qz>>4 | orig<<10
__device__ __forceinline__ uint2 pack_pt(float px, float py, float pz, int i) {
    int ix = min(max((int)(px * 16.0f), 0), 15);
    int iy = min(max((int)(py * 8.0f), 0), 7);
    int iz = min(max((int)(pz * 8.0f), 0), 7);
    int qx = min(max((int)((px * 16.0f - (float)ix) * 16384.0f), 0), 16383);
    int qy = min(max((int)((py * 8.0f  - (float)iy) * 16384.0f), 0), 16383);
    int qz = min(max((int)((pz * 8.0f  - (float)iz) * 16384.0f), 0), 16383);
    uint2 r;
    r.x = (unsigned)qx | ((unsigned)qy << 14) | ((unsigned)(qz & 0xF) << 28);
    r.y = (unsigned)(qz >> 4) | ((unsigned)i << 10);
    return r;
}

__global__ void __launch_bounds__(SC_THREADS)
cvn_scatter(const float* __restrict__ x, const int* __restrict__ P,
            uint2* __restrict__ sorted, int* __restrict__ rank, int n) {
    __shared__ int cnt[NB];                  // counts -> cursor
    __shared__ int excl[NB];                 // block-local exclusive
    __shared__ int Pb[NB];                   // global base per (block,bucket)
    __shared__ int wsum[16];
    __shared__ uint2 payload[PTS_PER_BLK];   // 64 KB
    __shared__ unsigned short bkt[PTS_PER_BLK];
    int t = threadIdx.x, b = blockIdx.x;
    int lane = t & 63, wid = t >> 6;
    int base = b * PTS_PER_BLK;
    cnt[t] = 0;
    Pb[t] = P[(size_t)b * NB + t];
    __syncthreads();

    float px[SC_PPT], py[SC_PPT], pz[SC_PPT];
    int qq[SC_PPT];
    #pragma unroll
    for (int k = 0; k < SC_PPT; ++k) {
        int i = base + k * SC_THREADS + t;
        if (i < n) {
            px[k] = x[3 * i]; py[k] = x[3 * i + 1]; pz[k] = x[3 * i + 2];
            qq[k] = bucket_of(px[k], py[k], pz[k]);
            atomicAdd(&cnt[qq[k]], 1);
        } else qq[k] = -1;
    }
    __syncthreads();

    // Block exclusive scan of cnt[1024] via wave scans (3 barriers).
    {
        int v = cnt[t];
        int incl = v;
        #pragma unroll
        for (int d = 1; d < 64; d <<= 1) {
            int u = __shfl_up(incl, d);
            if (lane >= d) incl += u;
        }
        if (lane == 63) wsum[wid] = incl;
        __syncthreads();
        if (t < 16) {
            int s = wsum[t];
            #pragma unroll
            for (int d = 1; d < 16; d <<= 1) {
                int u = __shfl_up(s, d);
                if (t >= d) s += u;
            }
            wsum[t] = s;
        }
        __syncthreads();
        int wexcl = (wid == 0) ? 0 : wsum[wid - 1];
        int e = wexcl + incl - v;
        excl[t] = e;
        cnt[t] = e;        // cursor
    }
    __syncthreads();

    #pragma unroll
    for (int k = 0; k < SC_PPT; ++k) {
        if (qq[k] >= 0) {
            int q = qq[k];
            int slot = atomicAdd(&cnt[q], 1);
            int i = base + k * SC_THREADS + t;
            payload[slot] = pack_pt(px[k], py[k], pz[k], i);
            bkt[slot] = (unsigned short)q;
            rank[i] = Pb[q] + (slot - excl[q]);   // coalesced in i
        }
    }
    __syncthreads();

    int total = min(n - base, PTS_PER_BLK);
    #pragma unroll
    for (int k = 0; k < SC_PPT; ++k) {
        int j = k * SC_THREADS + t;
        if (j < total) {
            int q = bkt[j];
            sorted[Pb[q] + (j - excl[q])] = payload[j];
        }
    }
}

__device__ __forceinline__ float4 lerp4(float4 a, float4 b, float w) {
    return make_float4(a.x + w * (b.x - a.x),
                       a.y + w * (b.y - a.y),
                       a.z + w * (b.z - a.z),
                       a.w + w * (b.w - a.w));
}

template <int RES>
__device__ __forceinline__ float4 level_val(const float4* __restrict__ V,
                                            float px, float py, float pz) {
    constexpr int S = RES + 1;
    float xs = fmodf(px * (float)RES, (float)RES);
    float ys = fmodf(py * (float)RES, (float)RES);
    float zs = fmodf(pz * (float)RES, (float)RES);
    float fx = floorf(xs), fy = floorf(ys), fz = floorf(zs);
    float tx = xs - fx, ty = ys - fy, tz = zs - fz;
    int ix = (int)fx, iy = (int)fy, iz = (int)fz;

    float wx = (3.0f - 2.0f * tx) * tx * tx;
    float wy = (3.0f - 2.0f * ty) * ty * ty;
    float wz = (3.0f - 2.0f * tz) * tz * tz;

    int base = (ix * S + iy) * S + iz;
    const float4* p0 = V + base;
    const float4* p1 = p0 + S * S;

    float4 c000 = p0[0];
    float4 c001 = p0[1];
    float4 c010 = p0[S];
    float4 c011 = p0[S + 1];
    float4 c100 = p1[0];
    float4 c101 = p1[1];
    float4 c110 = p1[S];
    float4 c111 = p1[S + 1];

    float4 m00 = lerp4(c000, c100, wx);
    float4 m01 = lerp4(c001, c101, wx);
    float4 m10 = lerp4(c010, c110, wx);
    float4 m11 = lerp4(c011, c111, wx);
    float4 n0  = lerp4(m00, m10, wy);
    float4 n1  = lerp4(m01, m11, wy);
    return lerp4(n0, n1, wz);
}

__device__ __forceinline__ float4 composite(const float4* __restrict__ V16,
                                            const float4* __restrict__ V32,
                                            const float4* __restrict__ V64,
                                            const float4* __restrict__ V128,
                                            float px, float py, float pz) {
    float4 acc = level_val<16>(V16, px, py, pz);
    float4 v;
    v = level_val<32>(V32, px, py, pz);
    acc.x += 0.5f * v.x; acc.y += 0.5f * v.y; acc.z += 0.5f * v.z; acc.w += 0.5f * v.w;
    v = level_val<64>(V64, px, py, pz);
    acc.x += 0.25f * v.x; acc.y += 0.25f * v.y; acc.z += 0.25f * v.z; acc.w += 0.25f * v.w;
    v = level_val<128>(V128, px, py, pz);
    acc.x += 0.125f * v.x; acc.y += 0.125f * v.y; acc.z += 0.125f * v.z; acc.w += 0.125f * v.w;
    return acc;
}

template <int R>
__device__ __forceinline__ float4 lds_interp(const float4* s,
                                             float px, float py, float pz,
                                             int fx, int fy, int fz) {
    constexpr int DIM = R + 1;
    float xs = px * (float)(16 * R);
    float ys = py * (float)(16 * R);
    float zs = pz * (float)(16 * R);
    int ixg = (int)xs, iyg = (int)ys, izg = (int)zs;
    float tx = xs - (float)ixg, ty = ys - (float)iyg, tz = zs - (float)izg;
    int lx = min(max(ixg - fx * R, 0), R - 1);
    int ly = min(max(iyg - fy * R, 0), R - 1);
    int lz = min(max(izg - fz * R, 0), R - 1);

    float wx = (3.0f - 2.0f * tx) * tx * tx;
    float wy = (3.0f - 2.0f * ty) * ty * ty;
    float wz = (3.0f - 2.0f * tz) * tz * tz;

    const float4* p0 = s + (lx * DIM + ly) * DIM + lz;
    const float4* p1 = p0 + DIM * DIM;
    float4 c000 = p0[0],   c001 = p0[1];
    float4 c010 = p0[DIM], c011 = p0[DIM + 1];
    float4 c100 = p1[0],   c101 = p1[1];
    float4 c110 = p1[DIM], c111 = p1[DIM + 1];

    float4 m00 = lerp4(c000, c100, wx);
    float4 m01 = lerp4(c001, c101, wx);
    float4 m10 = lerp4(c010, c110, wx);
    float4 m11 = lerp4(c011, c111, wx);
    float4 n0  = lerp4(m00, m10, wy);
    float4 n1  = lerp4(m01, m11, wy);
    return lerp4(n0, n1, wz);
}

// One WG per 1/16x1/8x1/8 bucket; 4 sub-cells (y/z halves).
__global__ void __launch_bounds__(MT)
cvn_main5(const uint2* __restrict__ sorted, const int* __restrict__ Tbase,
          const float4* __restrict__ V16, const float4* __restrict__ V32,
          const float4* __restrict__ V64, const float4* __restrict__ V128,
          float4* __restrict__ tmp, int n) {
    __shared__ uint2 pts[TILE];              // 19456 B packed points
    __shared__ float4 res[TILE];             // 38912 B results
    __shared__ unsigned short perm[TILE];    //  4864 B
    __shared__ int bins[4], hstart[5], cursor[4];
    __shared__ float4 s128[9 * 9 * 9];       // 11664 B
    __shared__ float4 s64[5 * 5 * 5];        //  2000 B
    __shared__ float4 s32[3 * 3 * 3];        //   432 B
    __shared__ float4 s16v[2 * 2 * 2];       //   128 B
    int t = threadIdx.x, b = blockIdx.x;
    int lane = t & 63;
    unsigned long long lanemask_lt = (lane == 0) ? 0ull : (~0ull >> (64 - lane));

    // XCD-compact mapping: b&7 -> octant of 16x8x8 bucket space.
    int ox = b & 1, oy = (b >> 1) & 1, oz = (b >> 2) & 1;
    int g  = b >> 3;
    int gx = g >> 4, gy = (g >> 2) & 3, gz = g & 3;
    int ix16 = ox * 8 + gx, iy8 = oy * 4 + gy, iz8 = oz * 4 + gz;
    int q = (ix16 * 8 + iy8) * 8 + iz8;

    int base = Tbase[q];
    int end  = (q == NB - 1) ? n : Tbase[q + 1];
    int len  = end - base;
    int lenT = min(len, TILE);

    if (t < 4) bins[t] = 0;
    __syncthreads();

    // Load + wave-aggregated 4-bin histogram. key = {qy bit13, qz bit13}.
    for (int p0 = 0; p0 < lenT; p0 += MT) {
        int p = p0 + t;
        int key = 4;
        if (p < lenT) {
            uint2 pk = sorted[base + p];
            pts[p] = pk;
            key = (int)(((pk.x >> 26) & 2u) | ((pk.y >> 9) & 1u));
        }
        unsigned long long m0 = __ballot(key == 0);
        unsigned long long m1 = __ballot(key == 1);
        unsigned long long m2 = __ballot(key == 2);
        unsigned long long m3 = __ballot(key == 3);
        if (lane == 0) {
            if (m0) atomicAdd(&bins[0], (int)__popcll(m0));
            if (m1) atomicAdd(&bins[1], (int)__popcll(m1));
            if (m2) atomicAdd(&bins[2], (int)__popcll(m2));
            if (m3) atomicAdd(&bins[3], (int)__popcll(m3));
        }
    }
    __syncthreads();

    if (t == 0) {
        int s = 0;
        #pragma unroll
        for (int k = 0; k < 4; ++k) { hstart[k] = s; cursor[k] = s; s += bins[k]; }
        hstart[4] = s;
    }
    __syncthreads();

    for (int p0 = 0; p0 < lenT; p0 += MT) {
        int p = p0 + t;
        int key = 4;
        if (p < lenT) {
            uint2 pk = pts[p];
            key = (int)(((pk.x >> 26) & 2u) | ((pk.y >> 9) & 1u));
        }
        unsigned long long m0 = __ballot(key == 0);
        unsigned long long m1 = __ballot(key == 1);
        unsigned long long m2 = __ballot(key == 2);
        unsigned long long m3 = __ballot(key == 3);
        int b0 = 0, b1 = 0, b2 = 0, b3 = 0;
        if (lane == 0) {
            if (m0) b0 = atomicAdd(&cursor[0], (int)__popcll(m0));
            if (m1) b1 = atomicAdd(&cursor[1], (int)__popcll(m1));
            if (m2) b2 = atomicAdd(&cursor[2], (int)__popcll(m2));
            if (m3) b3 = atomicAdd(&cursor[3], (int)__popcll(m3));
        }
        b0 = __shfl(b0, 0); b1 = __shfl(b1, 0);
        b2 = __shfl(b2, 0); b3 = __shfl(b3, 0);
        if (key < 4) {
            int slot;
            if      (key == 0) slot = b0 + (int)__popcll(m0 & lanemask_lt);
            else if (key == 1) slot = b1 + (int)__popcll(m1 & lanemask_lt);
            else if (key == 2) slot = b2 + (int)__popcll(m2 & lanemask_lt);
            else               slot = b3 + (int)__popcll(m3 & lanemask_lt);
            perm[slot] = (unsigned short)p;
        }
    }
    __syncthreads();

    const float inv16384 = 1.0f / 16384.0f;
    for (int s = 0; s < 4; ++s) {
        int fx = ix16;
        int fy = iy8 * 2 + (s >> 1);
        int fz = iz8 * 2 + (s & 1);

        if (t < 729) {
            int a = t / 81, bb = (t / 9) % 9, c = t % 9;
            s128[t] = V128[((size_t)(fx * 8 + a) * 129 + (fy * 8 + bb)) * 129
                           + (fz * 8 + c)];
        } else if (t < 729 + 125) {
            int u = t - 729;
            int a = u / 25, bb = (u / 5) % 5, c = u % 5;
            s64[u] = V64[((size_t)(fx * 4 + a) * 65 + (fy * 4 + bb)) * 65
                         + (fz * 4 + c)];
        } else if (t < 729 + 125 + 27) {
            int u = t - 729 - 125;
            int a = u / 9, bb = (u / 3) % 3, c = u % 3;
            s32[u] = V32[((size_t)(fx * 2 + a) * 33 + (fy * 2 + bb)) * 33
                         + (fz * 2 + c)];
        } else if (t < 729 + 125 + 27 + 8) {
            int u = t - 729 - 125 - 27;
            int a = u / 4, bb = (u / 2) % 2, c = u % 2;
            s16v[u] = V16[((size_t)(fx + a) * 17 + (fy + bb)) * 17 + (fz + c)];
        }
        __syncthreads();

        int p0 = hstart[s], p1 = hstart[s + 1];
        for (int p = p0 + t; p < p1; p += MT) {
            int j = perm[p];
            uint2 pk = pts[j];
            int qx = (int)(pk.x & 16383u);
            int qy = (int)((pk.x >> 14) & 16383u);
            int qz = (int)(((pk.x >> 28) | (pk.y << 4)) & 16383u);
            float px = ((float)ix16 + ((float)qx + 0.5f) * inv16384) * 0.0625f;
            float py = ((float)iy8  + ((float)qy + 0.5f) * inv16384) * 0.125f;
            float pz = ((float)iz8  + ((float)qz + 0.5f) * inv16384) * 0.125f;
            float4 acc = lds_interp<1>(s16v, px, py, pz, fx, fy, fz);
            float4 v;
            v = lds_interp<2>(s32, px, py, pz, fx, fy, fz);
            acc.x += 0.5f * v.x; acc.y += 0.5f * v.y;
            acc.z += 0.5f * v.z; acc.w += 0.5f * v.w;
            v = lds_interp<4>(s64, px, py, pz, fx, fy, fz);
            acc.x += 0.25f * v.x; acc.y += 0.25f * v.y;
            acc.z += 0.25f * v.z; acc.w += 0.25f * v.w;
            v = lds_interp<8>(s128, px, py, pz, fx, fy, fz);
            acc.x += 0.125f * v.x; acc.y += 0.125f * v.y;
            acc.z += 0.125f * v.z; acc.w += 0.125f * v.w;
            res[j] = acc;
        }
        __syncthreads();
    }

    for (int p = t; p < lenT; p += MT) tmp[base + p] = res[p];

    // Overflow tail (~never): global path on reconstructed coords.
    for (int p = lenT + t; p < len; p += MT) {
        uint2 pk = sorted[base + p];
        int qx = (int)(pk.x & 16383u);
        int qy = (int)((pk.x >> 14) & 16383u);
        int qz = (int)(((pk.x >> 28) | (pk.y << 4)) & 16383u);
        float px = ((float)ix16 + ((float)qx + 0.5f) * inv16384) * 0.0625f;
        float py = ((float)iy8  + ((float)qy + 0.5f) * inv16384) * 0.125f;
        float pz = ((float)iz8  + ((float)qz + 0.5f) * inv16384) * 0.125f;
        tmp[base + p] = composite(V16, V32, V64, V128, px, py, pz);
    }
}

__global__ void __launch_bounds__(256)
cvn_permute(const float4* __restrict__ tmp, const int* __restrict__ rank,
            float4* __restrict__ out, int n) {
    int i = blockIdx.x * 256 + (int)threadIdx.x;
    if (i >= n) return;
    out[i] = tmp[rank[i]];
}

__global__ void __launch_bounds__(256)
cvn_direct(const float* __restrict__ x,
           const float4* __restrict__ V16, const float4* __restrict__ V32,
           const float4* __restrict__ V64, const float4* __restrict__ V128,
           float4* __restrict__ out, int n) {
    int i = blockIdx.x * blockDim.x + threadIdx.x;
    if (i >= n) return;
    out[i] = composite(V16, V32, V64, V128, x[3 * i], x[3 * i + 1], x[3 * i + 2]);
}

extern "C" void kernel_launch(void* const* d_in, const int* in_sizes, int n_in,
                              void* d_out, int out_size, void* d_ws, size_t ws_size,
                              hipStream_t stream) {
    const float*  x    = (const float*)d_in[0];
    const float4* V16  = (const float4*)d_in[1];
    const float4* V32  = (const float4*)d_in[2];
    const float4* V64  = (const float4*)d_in[3];
    const float4* V128 = (const float4*)d_in[4];
    float4* out = (float4*)d_out;

    int n = in_sizes[0] / 3;
    int nblk = (n + PTS_PER_BLK - 1) / PTS_PER_BLK;
    int nch  = (nblk + CHUNK - 1) / CHUNK;

    auto align256 = [](size_t v) { return (v + 255) & ~(size_t)255; };
    size_t offP      = 0;
    size_t offS      = align256(offP + (size_t)nblk * NB * sizeof(int));
    size_t offSorted = align256(offS + (size_t)nch * NB * sizeof(int));
    size_t offRank   = align256(offSorted + (size_t)n * sizeof(uint2));
    size_t offTmp    = align256(offRank + (size_t)n * sizeof(int));
    size_t needFull  = offTmp + (size_t)n * sizeof(float4);

    int grid256 = (n + 255) / 256;

    if (ws_size >= needFull) {
        int*    P      = (int*)((char*)d_ws + offP);
        int*    S      = (int*)((char*)d_ws + offS);
        uint2*  sorted = (uint2*)((char*)d_ws + offSorted);
        int*    rank   = (int*)((char*)d_ws + offRank);
        float4* tmp    = (float4*)((char*)d_ws + offTmp);

        cvn_hist<<<nblk, H_THREADS, 0, stream>>>(x, P, n);
        cvn_scan_a<<<dim3(NB / 256, nch), 256, 0, stream>>>(P, S, nblk);
        cvn_scan_b<<<1, NB, 0, stream>>>(S, nch);
        cvn_scan_c<<<dim3(NB / 256, nch), 256, 0, stream>>>(P, S, nblk);
        cvn_scatter<<<nblk, SC_THREADS, 0, stream>>>(x, P, sorted, rank, n);
        cvn_main5<<<NB, MT, 0, stream>>>(sorted, S, V16, V32, V64, V128,
                                         tmp, n);
        cvn_permute<<<grid256, 256, 0, stream>>>(tmp, rank, out, n);
    } else {
        cvn_direct<<<grid256, 256, 0, stream>>>(x, V16, V32, V64, V128, out, n);
    }
}